// Round 1
// baseline (335.175 us; speedup 1.0000x reference)
//
#include <hip/hip_runtime.h>
#include <math.h>

// Problem-instance constants (B=16, N=8192, D=256 from setup_inputs)
#define BATCH 16
#define NDIM  8192
#define DDIM  256
#define IN_DIM (3*DDIM + 5)   // 773
#define NS2   64              // n-chunks for x stage-1

// gacc layout (ints): [0..15]=deg_sum, [16..31]=deg_sq, [32..47]=deg_max,
//                     [48..63]=nodes_per_graph, [64..79]=node_counts(mask)

__global__ void k_init(int* __restrict__ deg, int* __restrict__ gacc, int total_nodes) {
    int i = blockIdx.x * 256 + threadIdx.x;
    if (i < total_nodes) deg[i] = 0;
    if (i < 5 * BATCH) gacc[i] = 0;
}

// Degree histogram over row0 of edge_index, gated by same-graph check.
__global__ void k_edge(const int* __restrict__ e0, const int* __restrict__ e1,
                       const int* __restrict__ bv, int* __restrict__ deg, int E) {
    int base = (blockIdx.x * 256 + threadIdx.x) * 4;
    if (base + 3 < E) {
        int4 s = *(const int4*)(e0 + base);
        int4 d = *(const int4*)(e1 + base);
        if (bv[s.x] == bv[d.x]) atomicAdd(&deg[s.x], 1);
        if (bv[s.y] == bv[d.y]) atomicAdd(&deg[s.y], 1);
        if (bv[s.z] == bv[d.z]) atomicAdd(&deg[s.z], 1);
        if (bv[s.w] == bv[d.w]) atomicAdd(&deg[s.w], 1);
    } else if (base < E) {
        for (int e = base; e < E; ++e) {
            int s = e0[e], d = e1[e];
            if (bv[s] == bv[d]) atomicAdd(&deg[s], 1);
        }
    }
}

// Per-graph reductions of deg[] (sum, sumsq, max, count) via LDS int atomics.
__global__ void k_degred(const int* __restrict__ deg, const int* __restrict__ bv,
                         int* __restrict__ gacc, int total_nodes) {
    __shared__ int ls[BATCH], lq[BATCH], lm[BATCH], lc[BATCH];
    int t = threadIdx.x;
    if (t < BATCH) { ls[t] = 0; lq[t] = 0; lm[t] = 0; lc[t] = 0; }
    __syncthreads();
    int i = blockIdx.x * 256 + t;
    if (i < total_nodes) {
        int dg = deg[i];
        int b  = bv[i];
        atomicAdd(&ls[b], dg);
        atomicAdd(&lq[b], dg * dg);
        atomicMax(&lm[b], dg);
        atomicAdd(&lc[b], 1);
    }
    __syncthreads();
    if (t < BATCH) {
        if (ls[t]) atomicAdd(&gacc[t], ls[t]);
        if (lq[t]) atomicAdd(&gacc[BATCH + t], lq[t]);
        if (lm[t]) atomicMax(&gacc[2 * BATCH + t], lm[t]);
        if (lc[t]) atomicAdd(&gacc[3 * BATCH + t], lc[t]);
    }
}

// node_counts[b] = count of mask[b,0,n] > -1e8
__global__ void k_ncnt(const float* __restrict__ mask, int* __restrict__ gacc) {
    __shared__ int red[256];
    int b = blockIdx.x, t = threadIdx.x;
    int c = 0;
    for (int n = t; n < NDIM; n += 256) c += (mask[(size_t)b * NDIM + n] > -1.0e8f) ? 1 : 0;
    red[t] = c; __syncthreads();
    for (int s = 128; s > 0; s >>= 1) { if (t < s) red[t] += red[t + s]; __syncthreads(); }
    if (t == 0) gacc[4 * BATCH + b] = red[0];
}

// x stats stage 1: per (b, n-chunk) partial sum / sumsq / max for all 256 d.
// Thread t: d-quad = (t&63)*4 (float4), row-group rg = t>>6 (rows n0+rg+4k).
__global__ void k_xs1(const float* __restrict__ x, const float* __restrict__ mask,
                      float* __restrict__ part) {
    int ns = blockIdx.x, b = blockIdx.z;
    int t = threadIdx.x;
    int dbase = (t & 63) * 4, rg = t >> 6;
    const int chunk = NDIM / NS2;                 // 128
    int n0 = ns * chunk, n1 = n0 + chunk;
    const float* xb = x + (size_t)b * NDIM * DDIM;
    const float* mb = mask + (size_t)b * NDIM;
    float s0=0.f,s1=0.f,s2=0.f,s3=0.f;
    float q0=0.f,q1=0.f,q2=0.f,q3=0.f;
    float m0=-INFINITY,m1=-INFINITY,m2=-INFINITY,m3=-INFINITY;
    for (int n = n0 + rg; n < n1; n += 4) {
        float4 v = *(const float4*)(xb + (size_t)n * DDIM + dbase);
        float vf = (mb[n] > -1.0e8f) ? 1.f : 0.f;
        s0 += v.x * vf; q0 += v.x * v.x * vf;
        s1 += v.y * vf; q1 += v.y * v.y * vf;
        s2 += v.z * vf; q2 += v.z * v.z * vf;
        s3 += v.w * vf; q3 += v.w * v.w * vf;
        if (vf > 0.f) {
            m0 = fmaxf(m0, v.x); m1 = fmaxf(m1, v.y);
            m2 = fmaxf(m2, v.z); m3 = fmaxf(m3, v.w);
        }
    }
    __shared__ float4 Ls[256], Lq[256], Lm[256];
    Ls[t] = make_float4(s0, s1, s2, s3);
    Lq[t] = make_float4(q0, q1, q2, q3);
    Lm[t] = make_float4(m0, m1, m2, m3);
    __syncthreads();
    if (t < 64) {
        float4 a = Ls[t], b4 = Ls[t+64], c4 = Ls[t+128], d4 = Ls[t+192];
        float4 S = make_float4(a.x+b4.x+c4.x+d4.x, a.y+b4.y+c4.y+d4.y,
                               a.z+b4.z+c4.z+d4.z, a.w+b4.w+c4.w+d4.w);
        a = Lq[t]; b4 = Lq[t+64]; c4 = Lq[t+128]; d4 = Lq[t+192];
        float4 Q = make_float4(a.x+b4.x+c4.x+d4.x, a.y+b4.y+c4.y+d4.y,
                               a.z+b4.z+c4.z+d4.z, a.w+b4.w+c4.w+d4.w);
        a = Lm[t]; b4 = Lm[t+64]; c4 = Lm[t+128]; d4 = Lm[t+192];
        float4 M = make_float4(fmaxf(fmaxf(a.x,b4.x), fmaxf(c4.x,d4.x)),
                               fmaxf(fmaxf(a.y,b4.y), fmaxf(c4.y,d4.y)),
                               fmaxf(fmaxf(a.z,b4.z), fmaxf(c4.z,d4.z)),
                               fmaxf(fmaxf(a.w,b4.w), fmaxf(c4.w,d4.w)));
        size_t base = ((size_t)(b * NS2 + ns) * 3) * DDIM;
        *(float4*)(part + base + 0 * DDIM + 4 * t) = S;
        *(float4*)(part + base + 1 * DDIM + 4 * t) = Q;
        *(float4*)(part + base + 2 * DDIM + 4 * t) = M;
    }
}

// x stats stage 2: combine NS2 partials per (b,d), compute mean/max/std -> gf
__global__ void k_xs2(const float* __restrict__ part, const int* __restrict__ gacc,
                      float* __restrict__ gf) {
    int b = blockIdx.x, t = threadIdx.x;  // 256 threads, t = d
    float s = 0.f, q = 0.f, m = -INFINITY;
    for (int ns = 0; ns < NS2; ++ns) {
        size_t base = ((size_t)(b * NS2 + ns) * 3) * DDIM;
        s += part[base + t];
        q += part[base + DDIM + t];
        m = fmaxf(m, part[base + 2 * DDIM + t]);
    }
    float cnt  = (float)gacc[4 * BATCH + b];
    float mean = s / fmaxf(cnt, 1.f);
    float xmax = (cnt > 0.f) ? m : 0.f;
    float var  = (q - 2.f * mean * s + mean * mean * cnt) / fmaxf(cnt - 1.f, 1.f);
    float xstd = (cnt > 1.f) ? sqrtf(fmaxf(var, 0.f)) : 0.f;
    float* g = gf + (size_t)b * IN_DIM;
    g[t]            = mean;
    g[DDIM + t]     = xmax;
    g[2 * DDIM + t] = xstd;
}

// Structural features + 773->64->32->1 MLP + final scalars, one block.
__global__ void k_final(const float* __restrict__ gf_g, const int* __restrict__ gacc,
                        const float* __restrict__ W1, const float* __restrict__ B1,
                        const float* __restrict__ W2, const float* __restrict__ B2,
                        const float* __restrict__ W3, const float* __restrict__ B3,
                        float* __restrict__ out) {
    __shared__ float sgf[BATCH * IN_DIM];
    __shared__ float h1[BATCH * 64];
    __shared__ float h2[BATCH * 32];
    __shared__ float srnd[BATCH], sratio[BATCH], smaxa[BATCH];
    int t = threadIdx.x;
    for (int i = t; i < BATCH * IN_DIM; i += 256) sgf[i] = gf_g[i];
    __syncthreads();
    if (t < BATCH) {
        float nc   = (float)gacc[4 * BATCH + t];
        float npg  = (float)gacc[3 * BATCH + t];
        float Eb   = (float)gacc[t];
        float dsq  = (float)gacc[BATCH + t];
        float dmx  = (float)gacc[2 * BATCH + t];
        float num_edges = floorf(Eb * 0.5f);
        float npg_s = fmaxf(npg, 1.f);
        float dmean = Eb / npg_s;
        float dvar  = (dsq - npg * dmean * dmean) / fmaxf(npg - 1.f, 1.f);
        float dstd  = sqrtf(fmaxf(dvar, 0.f));
        bool  has   = (Eb > 0.f) && (nc > 1.f);
        float mxe   = nc * (nc - 1.f) * 0.5f;
        float density = has ? num_edges / fmaxf(mxe, 1.f) : 0.f;
        float avgdeg  = has ? dmean * 0.1f : 0.f;
        float maxdeg  = has ? dmx / fmaxf(nc, 1.f) : 0.f;
        float degstd  = (has && npg > 1.f) ? dstd * 0.1f : 0.f;
        float logsize = logf(nc + 1.f) * 0.2f;
        float* g = sgf + t * IN_DIM + 3 * DDIM;
        g[0] = logsize; g[1] = density; g[2] = avgdeg; g[3] = maxdeg; g[4] = degstd;
    }
    __syncthreads();
    for (int task = t; task < BATCH * 64; task += 256) {
        int b = task >> 6, j = task & 63;
        float acc = B1[j];
        const float* g = sgf + b * IN_DIM;
        for (int i = 0; i < IN_DIM; ++i) acc += g[i] * W1[i * 64 + j];
        h1[task] = fmaxf(acc, 0.f);
    }
    __syncthreads();
    for (int task = t; task < BATCH * 32; task += 256) {
        int b = task >> 5, j = task & 31;
        float acc = B2[j];
        const float* hb = h1 + b * 64;
        for (int i = 0; i < 64; ++i) acc += hb[i] * W2[i * 32 + j];
        h2[task] = fmaxf(acc, 0.f);
    }
    __syncthreads();
    if (t < BATCH) {
        float acc = B3[0];
        const float* hb = h2 + t * 32;
        for (int i = 0; i < 32; ++i) acc += hb[i] * W3[i];
        float score = 1.f / (1.f + expf(-acc));
        float ncc = 3.f + score * 47.f;
        float nc = (float)gacc[4 * BATCH + t];
        float safe_nc = fmaxf(nc, 1.f);
        float maxall = fminf(safe_nc, 50.f);
        float minall = fminf(maxall, 3.f);
        ncc = fmaxf(fminf(ncc, maxall), minall);
        srnd[t]   = rintf(ncc);          // half-to-even, matches jnp.round
        sratio[t] = ncc / safe_nc;
        smaxa[t]  = maxall;
    }
    __syncthreads();
    if (t == 0) {
        float sr = 0.f, sq = 0.f, mm = 1e30f;
        for (int b = 0; b < BATCH; ++b) { sr += srnd[b]; sq += sratio[b]; mm = fminf(mm, smaxa[b]); }
        int mbc = (int)mm;
        int ncf = (int)(sr / (float)BATCH);   // truncation matches astype(int32)
        if (ncf < 1) ncf = 1;
        if (ncf > mbc) ncf = mbc;
        out[0] = (float)ncf;
        out[1] = sq / (float)BATCH;
    }
}

extern "C" void kernel_launch(void* const* d_in, const int* in_sizes, int n_in,
                              void* d_out, int out_size, void* d_ws, size_t ws_size,
                              hipStream_t stream) {
    const float* x    = (const float*)d_in[0];
    const float* mask = (const float*)d_in[1];
    // d_in[2] (x_graph) is unused by the reference
    const int*   eidx = (const int*)d_in[3];
    const int*   bv   = (const int*)d_in[4];
    const float* W1   = (const float*)d_in[5];
    const float* B1   = (const float*)d_in[6];
    const float* W2   = (const float*)d_in[7];
    const float* B2   = (const float*)d_in[8];
    const float* W3   = (const float*)d_in[9];
    const float* B3   = (const float*)d_in[10];

    const int total_nodes = in_sizes[4];        // 131072
    const int E = in_sizes[3] / 2;              // 4194304 (row length)

    // workspace layout
    int*   deg  = (int*)d_ws;                   // total_nodes ints
    int*   gacc = deg + total_nodes;            // 5*BATCH ints
    float* gf   = (float*)(gacc + 5 * BATCH);   // BATCH*IN_DIM floats
    float* part = gf + BATCH * IN_DIM;          // BATCH*NS2*3*DDIM floats

    k_init  <<<(total_nodes + 255) / 256, 256, 0, stream>>>(deg, gacc, total_nodes);
    k_edge  <<<((E / 4) + 255) / 256,     256, 0, stream>>>(eidx, eidx + E, bv, deg, E);
    k_degred<<<(total_nodes + 255) / 256, 256, 0, stream>>>(deg, bv, gacc, total_nodes);
    k_ncnt  <<<BATCH,                     256, 0, stream>>>(mask, gacc);
    k_xs1   <<<dim3(NS2, 1, BATCH),       256, 0, stream>>>(x, mask, part);
    k_xs2   <<<BATCH,                     256, 0, stream>>>(part, gacc, gf);
    k_final <<<1,                         256, 0, stream>>>(gf, gacc, W1, B1, W2, B2, W3, B3,
                                                            (float*)d_out);
}